// Round 16
// baseline (378.902 us; speedup 1.0000x reference)
//
#include <hip/hip_runtime.h>

#define NN 50000
#define DD 128
#define EE 500000

#define PREP_CVT 3125   // ND/(256*8)
#define PREP_W   256
#define PREP_E   1954   // ceil(EE/256)
#define SCAN_B   196    // ceil(NN/256)

typedef __attribute__((ext_vector_type(8))) unsigned short ushort8;
typedef __attribute__((ext_vector_type(8))) short bf16x8v;   // 8 bf16 in 4 VGPRs
typedef __attribute__((ext_vector_type(4))) float f32x4;

static __device__ __forceinline__ unsigned short f2bf(float f) {
    unsigned int u = __float_as_uint(f);
    unsigned int r = (u + 0x7fffu + ((u >> 16) & 1u)) >> 16;
    return (unsigned short)r;
}
static __device__ __forceinline__ float bf2f(unsigned short s) {
    return __uint_as_float(((unsigned int)s) << 16);
}

// ---------------- fused prep: cvt (A1 self half) | wprep (Bt) | degi (histogram) ----------------
__global__ __launch_bounds__(256) void prep_kernel(const float* __restrict__ h,
                                                   unsigned short* __restrict__ A1,
                                                   const float* __restrict__ Ws1,
                                                   const float* __restrict__ Wn1,
                                                   const float* __restrict__ Ws2,
                                                   const float* __restrict__ Wn2,
                                                   unsigned short* __restrict__ Bt1,
                                                   unsigned short* __restrict__ Bt2,
                                                   const int* __restrict__ dst0,
                                                   const int* __restrict__ dst1,
                                                   int* __restrict__ deg0,
                                                   int* __restrict__ deg1) {
    int blk = blockIdx.x;
    if (blk < PREP_CVT) {
        // A1[m][0..127] = bf16(2*h[m][d])
        size_t i = ((size_t)blk * 256 + threadIdx.x) * 8;
        int m = (int)(i >> 7);
        int d = (int)(i & 127);
        float4 a = *reinterpret_cast<const float4*>(&h[i]);
        float4 b = *reinterpret_cast<const float4*>(&h[i + 4]);
        ushort8 o;
        o[0] = f2bf(2.f * a.x); o[1] = f2bf(2.f * a.y); o[2] = f2bf(2.f * a.z); o[3] = f2bf(2.f * a.w);
        o[4] = f2bf(2.f * b.x); o[5] = f2bf(2.f * b.y); o[6] = f2bf(2.f * b.z); o[7] = f2bf(2.f * b.w);
        *reinterpret_cast<ushort8*>(&A1[(size_t)m * 256 + d]) = o;
    } else if (blk < PREP_CVT + PREP_W) {
        // Bt[n][k] bf16, k in [0,256) = [Ws ; Wn]
        int t = (blk - PREP_CVT) * 256 + threadIdx.x;  // 0..65535
        int lay = t >> 15;
        int r = t & 32767;
        int k = r >> 7;
        int n = r & 127;
        const float* Ws = lay ? Ws2 : Ws1;
        const float* Wn = lay ? Wn2 : Wn1;
        unsigned short* Bt = lay ? Bt2 : Bt1;
        float v = (k < 128) ? Ws[(size_t)k * 128 + n] : Wn[(size_t)(k - 128) * 128 + n];
        Bt[(size_t)n * 256 + k] = f2bf(v);
    } else {
        int e = (blk - PREP_CVT - PREP_W) * 256 + threadIdx.x;
        if (e < EE) {
            atomicAdd(&deg0[dst0[e]], 1);
            atomicAdd(&deg1[dst1[e]], 1);
        }
    }
}

// ---------------- scan phase 1: per-block sums of deg ----------------
__global__ __launch_bounds__(256) void scan1_kernel(const int* __restrict__ deg0,
                                                    const int* __restrict__ deg1,
                                                    int* __restrict__ part) {
    int b = blockIdx.x;                 // 0..2*SCAN_B-1
    int type = (b >= SCAN_B);
    int bb = b - type * SCAN_B;
    const int* deg = type ? deg1 : deg0;
    int i = bb * 256 + threadIdx.x;
    int v = (i < NN) ? deg[i] : 0;
    __shared__ int s[256];
    s[threadIdx.x] = v;
    __syncthreads();
    for (int off = 1; off < 256; off <<= 1) {
        int t = (threadIdx.x >= off) ? s[threadIdx.x - off] : 0;
        __syncthreads();
        s[threadIdx.x] += t;
        __syncthreads();
    }
    if (threadIdx.x == 255) part[b] = s[255];
}

// ---------------- scan phase 2: exclusive scan of partials (1 block) ----------------
__global__ __launch_bounds__(256) void scan2_kernel(int* __restrict__ part) {
    __shared__ int s[256];
    for (int type = 0; type < 2; ++type) {
        int idx = type * SCAN_B + threadIdx.x;
        int v = (threadIdx.x < SCAN_B) ? part[idx] : 0;
        s[threadIdx.x] = v;
        __syncthreads();
        for (int off = 1; off < 256; off <<= 1) {
            int t = (threadIdx.x >= off) ? s[threadIdx.x - off] : 0;
            __syncthreads();
            s[threadIdx.x] += t;
            __syncthreads();
        }
        if (threadIdx.x < SCAN_B) part[idx] = s[threadIdx.x] - v;  // exclusive
        __syncthreads();
    }
}

// ---------------- scan phase 3: rp = excl prefix; cur = rp; rdeg = 1/max(deg,1) ----------------
__global__ __launch_bounds__(256) void scan3_kernel(const int* __restrict__ deg0,
                                                    const int* __restrict__ deg1,
                                                    const int* __restrict__ part,
                                                    int* __restrict__ rp0,
                                                    int* __restrict__ rp1,
                                                    int* __restrict__ cur0,
                                                    int* __restrict__ cur1,
                                                    float* __restrict__ rdeg0,
                                                    float* __restrict__ rdeg1) {
    int b = blockIdx.x;
    int type = (b >= SCAN_B);
    int bb = b - type * SCAN_B;
    const int* deg = type ? deg1 : deg0;
    int* rp  = type ? rp1 : rp0;
    int* cur = type ? cur1 : cur0;
    float* rdeg = type ? rdeg1 : rdeg0;
    int i = bb * 256 + threadIdx.x;
    int v = (i < NN) ? deg[i] : 0;
    __shared__ int s[256];
    s[threadIdx.x] = v;
    __syncthreads();
    for (int off = 1; off < 256; off <<= 1) {
        int t = (threadIdx.x >= off) ? s[threadIdx.x - off] : 0;
        __syncthreads();
        s[threadIdx.x] += t;
        __syncthreads();
    }
    int excl = s[threadIdx.x] - v + part[b];
    if (i < NN) {
        rp[i] = excl;
        cur[i] = excl;
        rdeg[i] = 1.0f / fmaxf((float)v, 1.0f);
        if (i == NN - 1) rp[NN] = excl + v;
    }
}

// ---------------- scatter edges into CSR (cur pre-initialized to rp) ----------------
__global__ __launch_bounds__(256) void fill_kernel(const int* __restrict__ src0,
                                                   const int* __restrict__ dst0,
                                                   const int* __restrict__ src1,
                                                   const int* __restrict__ dst1,
                                                   int* __restrict__ cur0,
                                                   int* __restrict__ csr0,
                                                   int* __restrict__ cur1,
                                                   int* __restrict__ csr1) {
    int e = blockIdx.x * 256 + threadIdx.x;
    if (e < EE) {
        int p0 = atomicAdd(&cur0[dst0[e]], 1);
        csr0[p0] = src0[e];
        int p1 = atomicAdd(&cur1[dst1[e]], 1);
        csr1[p1] = src1[e];
    }
}

// ---------------- gather: A[node][128+c] = bf16( mean0 + mean1 ) ----------------
// reads self half A[s][0..127] (= bf16(2*x[s])); 0.5 folded into rdeg.
__global__ __launch_bounds__(256) void agg_gather_kernel(unsigned short* __restrict__ A,
                                                         const int* __restrict__ rp0,
                                                         const int* __restrict__ csr0,
                                                         const int* __restrict__ rp1,
                                                         const int* __restrict__ csr1,
                                                         const float* __restrict__ rdeg0,
                                                         const float* __restrict__ rdeg1) {
    int tid  = threadIdx.x;
    int node = blockIdx.x * 4 + (tid >> 6);
    int lane = tid & 63;
    int sub  = lane >> 4;   // neighbor slot 0..3
    int lc   = lane & 15;   // col chunk of 8 bf16

    float a0[8] = {0.f, 0.f, 0.f, 0.f, 0.f, 0.f, 0.f, 0.f};
    float a1[8] = {0.f, 0.f, 0.f, 0.f, 0.f, 0.f, 0.f, 0.f};

    int b0 = rp0[node], e0 = rp0[node + 1];
    for (int e = b0 + sub; e < e0; e += 4) {
        int s = csr0[e];
        ushort8 v = *reinterpret_cast<const ushort8*>(&A[(size_t)s * 256 + lc * 8]);
#pragma unroll
        for (int j = 0; j < 8; ++j) a0[j] += bf2f(v[j]);
    }
    int b1 = rp1[node], e1 = rp1[node + 1];
    for (int e = b1 + sub; e < e1; e += 4) {
        int s = csr1[e];
        ushort8 v = *reinterpret_cast<const ushort8*>(&A[(size_t)s * 256 + lc * 8]);
#pragma unroll
        for (int j = 0; j < 8; ++j) a1[j] += bf2f(v[j]);
    }

    float r0 = 0.5f * rdeg0[node], r1 = 0.5f * rdeg1[node];
    float g[8];
#pragma unroll
    for (int j = 0; j < 8; ++j) {
        g[j] = a0[j] * r0 + a1[j] * r1;
        g[j] += __shfl_xor(g[j], 16);
        g[j] += __shfl_xor(g[j], 32);
    }
    if (sub == 0) {
        ushort8 o;
#pragma unroll
        for (int j = 0; j < 8; ++j) o[j] = f2bf(g[j]);
        *reinterpret_cast<ushort8*>(&A[(size_t)node * 256 + 128 + lc * 8]) = o;
    }
}

// ---------------- MFMA GEMM: out[m][n] = A[m][0..255] @ Bt[n][0..255] + 2*b[n] ----------------
// 64 rows/block, 4 waves x 16 rows; 8 col-frags x 8 k-steps of mfma_f32_16x16x32_bf16.
// C/D: col = lane&15, row = 4*(lane>>4)+reg  [m89-verified].
__global__ __launch_bounds__(256) void mfma_gemm_kernel(const unsigned short* __restrict__ A,
                                                        const unsigned short* __restrict__ Bt,
                                                        const float* __restrict__ bias,
                                                        float* __restrict__ outf,
                                                        unsigned short* __restrict__ a2self,
                                                        int relu) {
    const int tid  = threadIdx.x;
    const int wave = tid >> 6;
    const int lane = tid & 63;
    const int lr   = lane & 15;
    const int lk   = (lane >> 4) * 8;
    const int rowbase = blockIdx.x * 64 + wave * 16;

    int arow = rowbase + lr;
    if (arow >= NN) arow = NN - 1;  // clamp (stores are guarded)
    const unsigned short* Ap = A + (size_t)arow * 256 + lk;
    const unsigned short* Bp = Bt + (size_t)lr * 256 + lk;

    f32x4 acc[8];
#pragma unroll
    for (int cf = 0; cf < 8; ++cf) acc[cf] = (f32x4){0.f, 0.f, 0.f, 0.f};

    for (int ks = 0; ks < 8; ++ks) {
        bf16x8v a = *reinterpret_cast<const bf16x8v*>(Ap + ks * 32);
#pragma unroll
        for (int cf = 0; cf < 8; ++cf) {
            bf16x8v b = *reinterpret_cast<const bf16x8v*>(Bp + cf * (16 * 256) + ks * 32);
            acc[cf] = __builtin_amdgcn_mfma_f32_16x16x32_bf16(a, b, acc[cf], 0, 0, 0);
        }
    }

    const int rfrag = (lane >> 4) * 4;
#pragma unroll
    for (int cf = 0; cf < 8; ++cf) {
        int col = cf * 16 + lr;
        float bb = 2.0f * bias[col];
#pragma unroll
        for (int rg = 0; rg < 4; ++rg) {
            int r = rowbase + rfrag + rg;
            if (r < NN) {
                float v = acc[cf][rg] + bb;
                if (relu) v = fmaxf(v, 0.f);
                if (outf) {
                    outf[(size_t)r * 128 + col] = v;
                } else {
                    a2self[(size_t)r * 256 + col] = f2bf(2.0f * v);
                }
            }
        }
    }
}

extern "C" void kernel_launch(void* const* d_in, const int* in_sizes, int n_in,
                              void* d_out, int out_size, void* d_ws, size_t ws_size,
                              hipStream_t stream) {
    (void)in_sizes; (void)n_in; (void)out_size; (void)ws_size;

    const float* h    = (const float*)d_in[0];
    const int*   src0 = (const int*)d_in[1];
    const int*   dst0 = (const int*)d_in[2];
    const int*   src1 = (const int*)d_in[3];
    const int*   dst1 = (const int*)d_in[4];
    const float* Ws1  = (const float*)d_in[5];
    const float* Wn1  = (const float*)d_in[6];
    const float* b1   = (const float*)d_in[7];
    const float* Ws2  = (const float*)d_in[8];
    const float* Wn2  = (const float*)d_in[9];
    const float* b2   = (const float*)d_in[10];
    float* out = (float*)d_out;

    const size_t ND2 = (size_t)NN * 256;  // 12.8M

    unsigned short* A1  = (unsigned short*)d_ws;  // ND2
    unsigned short* A2  = A1 + ND2;               // ND2
    unsigned short* Bt1 = A2 + ND2;               // 32768
    unsigned short* Bt2 = Bt1 + 32768;            // 32768
    float* rdeg0 = (float*)(Bt2 + 32768);         // NN
    float* rdeg1 = rdeg0 + NN;                    // NN
    int* deg0 = (int*)(rdeg1 + NN);               // NN
    int* deg1 = deg0 + NN;                        // NN
    int* cur0 = deg1 + NN;                        // NN
    int* cur1 = cur0 + NN;                        // NN
    int* rp0  = cur1 + NN;                        // NN+1
    int* rp1  = rp0 + NN + 1;                     // NN+1
    int* part = rp1 + NN + 1;                     // 2*SCAN_B
    int* csr0 = part + 2 * SCAN_B;                // EE
    int* csr1 = csr0 + EE;                        // EE

    const int prepBlocks = PREP_CVT + PREP_W + PREP_E;  // 5335
    const int aggBlocks  = NN / 4;                      // 12500 exact
    const int gemmBlocks = (NN + 63) / 64;              // 782

    // ---- prep (cvt | wprep | degi) + 3-phase scan + fill ----
    hipMemsetAsync(deg0, 0, 2 * (size_t)NN * sizeof(int), stream);  // deg0,deg1
    prep_kernel<<<prepBlocks, 256, 0, stream>>>(h, A1, Ws1, Wn1, Ws2, Wn2, Bt1, Bt2,
                                                dst0, dst1, deg0, deg1);
    scan1_kernel<<<2 * SCAN_B, 256, 0, stream>>>(deg0, deg1, part);
    scan2_kernel<<<1, 256, 0, stream>>>(part);
    scan3_kernel<<<2 * SCAN_B, 256, 0, stream>>>(deg0, deg1, part,
                                                 rp0, rp1, cur0, cur1, rdeg0, rdeg1);
    fill_kernel<<<PREP_E, 256, 0, stream>>>(src0, dst0, src1, dst1,
                                            cur0, csr0, cur1, csr1);

    // ---- layer 1 ----
    agg_gather_kernel<<<aggBlocks, 256, 0, stream>>>(A1, rp0, csr0, rp1, csr1, rdeg0, rdeg1);
    mfma_gemm_kernel<<<gemmBlocks, 256, 0, stream>>>(A1, Bt1, b1, nullptr, A2, 1);

    // ---- layer 2 ----
    agg_gather_kernel<<<aggBlocks, 256, 0, stream>>>(A2, rp0, csr0, rp1, csr1, rdeg0, rdeg1);
    mfma_gemm_kernel<<<gemmBlocks, 256, 0, stream>>>(A2, Bt2, b2, out, nullptr, 0);
}